// Round 2
// baseline (770.231 us; speedup 1.0000x reference)
//
#include <hip/hip_runtime.h>

typedef __attribute__((ext_vector_type(8))) short short8;
typedef __attribute__((ext_vector_type(4))) float floatx4;

__device__ inline short f2bf(float v) {
    unsigned u = __builtin_bit_cast(unsigned, v);
    unsigned r = (u + 0x7fffu + ((u >> 16) & 1u)) >> 16;
    return (short)r;
}
__device__ inline float bf2f(short s) {
    unsigned u = ((unsigned)(unsigned short)s) << 16;
    return __builtin_bit_cast(float, u);
}

// spline weights for value v: 8 kept bases of the uniform cubic B-spline
__device__ inline void spline8(float v, short* arr) {
    float u = (v + 2.2f) * 2.5f;
    float fj = floorf(u);
    int jj = (int)fj;
    float t1 = u - fj;
    float ok = (jj >= 0 && jj <= 10) ? (1.f / 6.f) : 0.f;
    float t2 = t1 * t1, t3 = t2 * t1;
    float omt = 1.f - t1;
    short sw0 = f2bf(omt * omt * omt * ok);
    short sw1 = f2bf((3.f * t3 - 6.f * t2 + 4.f) * ok);
    short sw2 = f2bf((-3.f * t3 + 3.f * t2 + 3.f * t1 + 1.f) * ok);
    short sw3 = f2bf(t3 * ok);
#pragma unroll
    for (int s = 0; s < 8; ++s) {
        int rr = s - jj + 3;
        arr[s] = (rr == 0) ? sw0 : (rr == 1) ? sw1 : (rr == 2) ? sw2
                 : (rr == 3) ? sw3 : (short)0;
    }
}

// ---------------------------------------------------------------------------
// gemm256: 256x128 tile, BK=32, 8 waves (512 thr), wave tile 64x64.
// Same proven 2-barrier global_load_lds schedule as round-1's gemm128 —
// only tiling constants change. 85.3 FLOP per staged byte (vs 64).
// Split-K over concatenated 2-segment K; fp32 partials at C + s*sSplit.
// Grid must be (16, 4, 3*S); XCD remap: each XCD owns 2 M-slabs x 4 N
// per (z,s), N fastest in time so the A-slab + W panel (~3.5MB) stay in L2.
// __launch_bounds__(512,4): cap VGPR at 128 -> 2 blocks (16 waves)/CU.
// ---------------------------------------------------------------------------
__global__ __launch_bounds__(512, 4) void gemm256(
    int S, int Kh,
    const short* __restrict__ A0, int lda0, long sA0, int K0,
    const short* __restrict__ W0, int ldw0, long sW0,
    const short* __restrict__ A1, int lda1, long sA1, int K1,
    const short* __restrict__ W1, int ldw1, long sW1,
    float* __restrict__ C, int ldc, long sC, long sSplit)
{
    __shared__ short As[256 * 32];
    __shared__ short Ws[128 * 32];
    const int t = threadIdx.x;
    // dispatch linear id (x fastest); XCD k8 = id%8
    int n = blockIdx.x + (blockIdx.y << 4) + (blockIdx.z << 6);
    int k8 = n & 7, j = n >> 3;
    int byi = j & 3;                       // N-block fastest within XCD
    int bxi = (k8 << 1) + ((j >> 2) & 1);  // 2 M-slabs per XCD
    int bzi = j >> 3;                      // (z,s) slowest
    const int z = bzi / S, s = bzi % S;
    const int bm = bxi * 256, bn = byi * 128;
    const int lane = t & 63, w = t >> 6;
    const int wm = (w >> 1) * 64, wn = (w & 1) * 64;
    const int lrow = lane & 15, quad = lane >> 4;

    floatx4 acc[4][4] = {};

    const int kbeg = s * Kh, kend = kbeg + Kh;

    const short* A = A0 + (long)z * sA0;
    const short* W = W0 + (long)z * sW0;
    int lda = lda0, ldw = ldw0;
    int kb = kbeg, ke = (kend < K0) ? kend : K0;   // seg0 window

    for (int seg = 0; seg < 2; ++seg) {
        for (int kv = kb; kv < ke; kv += 32) {
#pragma unroll
            for (int i = 0; i < 2; ++i) {          // A: 256x32 = 1024 chunks
                int c = i * 512 + t;
                int row = c >> 2, cg = (c & 3) * 8;
                const short* gp = A + (long)(bm + row) * lda + kv + cg;
                __builtin_amdgcn_global_load_lds(
                    (const __attribute__((address_space(1))) void*)gp,
                    (__attribute__((address_space(3))) void*)(As + c * 8), 16, 0, 0);
            }
            {                                      // W: 128x32 = 512 chunks
                int row = t >> 2, cg = (t & 3) * 8;
                const short* gq = W + (long)(bn + row) * ldw + kv + cg;
                __builtin_amdgcn_global_load_lds(
                    (const __attribute__((address_space(1))) void*)gq,
                    (__attribute__((address_space(3))) void*)(Ws + t * 8), 16, 0, 0);
            }
            __syncthreads();
            short8 af[4], bfr[4];
#pragma unroll
            for (int mi = 0; mi < 4; ++mi)
                af[mi] = *(const short8*)(As + (wm + mi * 16 + lrow) * 32 + quad * 8);
#pragma unroll
            for (int ni = 0; ni < 4; ++ni)
                bfr[ni] = *(const short8*)(Ws + (wn + ni * 16 + lrow) * 32 + quad * 8);
#pragma unroll
            for (int mi = 0; mi < 4; ++mi)
#pragma unroll
                for (int ni = 0; ni < 4; ++ni)
                    acc[mi][ni] = __builtin_amdgcn_mfma_f32_16x16x32_bf16(
                        af[mi], bfr[ni], acc[mi][ni], 0, 0, 0);
            __syncthreads();
        }
        // segment-1 window (empty loop if this split doesn't reach seg1)
        A = A1 + (long)z * sA1;
        W = W1 + (long)z * sW1;
        lda = lda1; ldw = ldw1;
        kb = ((kbeg > K0) ? kbeg : K0) - K0;
        ke = kend - K0;
    }

    float* Cz = C + (long)z * sC + (long)s * sSplit;
#pragma unroll
    for (int mi = 0; mi < 4; ++mi)
#pragma unroll
        for (int ni = 0; ni < 4; ++ni)
#pragma unroll
            for (int r = 0; r < 4; ++r) {
                int row = bm + wm + mi * 16 + quad * 4 + r;
                int col = bn + wn + ni * 16 + lrow;
                Cz[(long)row * ldc + col] = acc[mi][ni][r];
            }
}

// ---------------------------------------------------------------------------
// gemm64: retained (round-4-proven) for the two small GEMMs (gates, ogate).
// Tile 64x128, BK=32, 4 waves, bf16 out. Called with swz=0 only.
// ---------------------------------------------------------------------------
__global__ __launch_bounds__(256) void gemm64(
    int swz,
    const short* __restrict__ A0, int lda0, long sA0, int K0,
    const short* __restrict__ W0, int ldw0, long sW0,
    const short* __restrict__ A1, int lda1, long sA1, int K1,
    const short* __restrict__ W1, int ldw1, long sW1,
    short* __restrict__ C, int ldc, long sC)
{
    __shared__ short As[64 * 32];
    __shared__ short Ws[128 * 32];
    const int t = threadIdx.x;
    int bxi = blockIdx.x, byi = blockIdx.y, bzi = blockIdx.z;
    if (swz) {                       // grid must be (64,4,3)
        int n = bxi + (byi << 6) + (bzi << 8);
        int k = n & 7, j = n >> 3;
        byi = j & 3;
        bxi = k * 8 + ((j >> 2) & 7);
        bzi = j >> 5;
    }
    const int z = bzi;
    const int bm = bxi * 64;
    const int bn = byi * 128;
    const int lane = t & 63, w = t >> 6;
    const int wm = (w >> 1) * 32, wn = (w & 1) * 64;
    const int lrow = lane & 15, quad = lane >> 4;

    floatx4 acc[2][4] = {};

    const short* A = A0 + (long)z * sA0;
    const short* W = W0 + (long)z * sW0;
    int K = K0, lda = lda0, ldw = ldw0;

    for (int seg = 0; seg < 2; ++seg) {
        for (int k0 = 0; k0 < K; k0 += 32) {
            {   // A: 64x32 = 256 16B chunks, one per thread
                int row = t >> 2, cg = (t & 3) * 8;
                const short* gp = A + (long)(bm + row) * lda + k0 + cg;
                __builtin_amdgcn_global_load_lds(
                    (const __attribute__((address_space(1))) void*)gp,
                    (__attribute__((address_space(3))) void*)(As + t * 8), 16, 0, 0);
            }
#pragma unroll
            for (int j = 0; j < 2; ++j) {  // W: 128x32 = 512 chunks, two per thread
                int cj = j * 256 + t;
                int row = cj >> 2, cg = (cj & 3) * 8;
                const short* gq = W + (long)(bn + row) * ldw + k0 + cg;
                __builtin_amdgcn_global_load_lds(
                    (const __attribute__((address_space(1))) void*)gq,
                    (__attribute__((address_space(3))) void*)(Ws + cj * 8), 16, 0, 0);
            }
            __syncthreads();
            short8 af[2], bfr[4];
#pragma unroll
            for (int mi = 0; mi < 2; ++mi)
                af[mi] = *(const short8*)(As + (wm + mi * 16 + lrow) * 32 + quad * 8);
#pragma unroll
            for (int ni = 0; ni < 4; ++ni)
                bfr[ni] = *(const short8*)(Ws + (wn + ni * 16 + lrow) * 32 + quad * 8);
#pragma unroll
            for (int mi = 0; mi < 2; ++mi)
#pragma unroll
                for (int ni = 0; ni < 4; ++ni)
                    acc[mi][ni] = __builtin_amdgcn_mfma_f32_16x16x32_bf16(
                        af[mi], bfr[ni], acc[mi][ni], 0, 0, 0);
            __syncthreads();
        }
        A = A1 + (long)z * sA1; W = W1 + (long)z * sW1;
        K = K1; lda = lda1; ldw = ldw1;
    }

    short* Cz = C + (long)z * sC;
#pragma unroll
    for (int mi = 0; mi < 2; ++mi)
#pragma unroll
        for (int ni = 0; ni < 4; ++ni)
#pragma unroll
            for (int r = 0; r < 4; ++r) {
                int row = bm + wm + mi * 16 + quad * 4 + r;
                int col = bn + wn + ni * 16 + lrow;
                Cz[(long)row * ldc + col] = f2bf(acc[mi][ni][r]);
            }
}

// ---------------------------------------------------------------------------
// megapack4: all weight fp32->bf16 packs, float4 loads / short4 stores.
// 4 elems/thread. grid: 26880 blocks x 256
// ---------------------------------------------------------------------------
__global__ __launch_bounds__(256) void megapack4(
    const float* __restrict__ wx_b, const float* __restrict__ wx_s,
    const float* __restrict__ wh_b, const float* __restrict__ wh_s,
    const float* __restrict__ hz_b, const float* __restrict__ hz_s,
    const float* __restrict__ phi_b, const float* __restrict__ phi_s,
    const float* __restrict__ hh_w, const float* __restrict__ o_w,
    const float* __restrict__ f_w, const float* __restrict__ i_w,
    const float* __restrict__ g_w,
    short* __restrict__ Wx, short* __restrict__ Wh, short* __restrict__ Whz,
    short* __restrict__ Wphi, short* __restrict__ HHb, short* __restrict__ OWb,
    short* __restrict__ Wg)
{
    int bid = blockIdx.x, tid = threadIdx.x;
    float4 v;
    short* dst;
    long e;
    if (bid < 3456) {                        // Wx: (1536, 2304) kan-pack
        e = ((long)bid * 256 + tid) * 4;
        int r = (int)(e / 2304), c = (int)(e % 2304);
        v = (c < 256) ? *(const float4*)(wx_b + (long)r * 256 + c)
                      : *(const float4*)(wx_s + (long)r * 2048 + (c - 256));
        dst = Wx + e;
    } else if (bid < 24192) {                // Wh/Whz/Wphi: (1536, 4608) each
        int jb = bid - 3456;
        int job = jb / 6912, lb = jb % 6912;
        const float* bp = (job == 0) ? wh_b : (job == 1) ? hz_b : phi_b;
        const float* sp = (job == 0) ? wh_s : (job == 1) ? hz_s : phi_s;
        short* dp = (job == 0) ? Wh : (job == 1) ? Whz : Wphi;
        e = ((long)lb * 256 + tid) * 4;
        int r = (int)(e / 4608), c = (int)(e % 4608);
        v = (c < 512) ? *(const float4*)(bp + (long)r * 512 + c)
                      : *(const float4*)(sp + (long)r * 4096 + (c - 512));
        dst = dp + e;
    } else if (bid < 24960) {                // hh_w flat 786432
        e = ((long)(bid - 24192) * 256 + tid) * 4;
        v = *(const float4*)(hh_w + e);
        dst = HHb + e;
    } else if (bid < 25728) {                // o_w flat 786432
        e = ((long)(bid - 24960) * 256 + tid) * 4;
        v = *(const float4*)(o_w + e);
        dst = OWb + e;
    } else if (bid < 26112) {                // f_w flat 393216
        e = ((long)(bid - 25728) * 256 + tid) * 4;
        v = *(const float4*)(f_w + e);
        dst = Wg + e;
    } else if (bid < 26496) {                // i_w
        e = ((long)(bid - 26112) * 256 + tid) * 4;
        v = *(const float4*)(i_w + e);
        dst = Wg + 393216 + e;
    } else {                                 // g_w
        e = ((long)(bid - 26496) * 256 + tid) * 4;
        v = *(const float4*)(g_w + e);
        dst = Wg + 786432 + e;
    }
    dst[0] = f2bf(v.x); dst[1] = f2bf(v.y);
    dst[2] = f2bf(v.z); dst[3] = f2bf(v.w);
}

// ---------------------------------------------------------------------------
// prep_acts: x expand -> Xe + Agate[:,0:256]; h cast -> Agate[:,256:768];
// z expand -> Ze + zraw.  grid: 36864 blocks x 256
// ---------------------------------------------------------------------------
__global__ __launch_bounds__(256) void prep_acts(
    const float* __restrict__ x_t, const float* __restrict__ h_prev,
    const float* __restrict__ z_prev,
    short* __restrict__ Xe, short* __restrict__ Agate,
    short* __restrict__ Ze, short* __restrict__ zraw)
{
    int bid = blockIdx.x, tid = threadIdx.x;
    if (bid < 4096) {                        // x: row bid, col tid
        int r = bid, i = tid;
        float v = x_t[(long)r * 256 + i];
        Agate[(long)r * 768 + i] = f2bf(v);
        long ob = (long)r * 2304;
        Xe[ob + i] = f2bf(v / (1.f + __expf(-v)));
        short arr[8];
        spline8(v, arr);
        *(short8*)(Xe + ob + 256 + (long)i * 8) = *(const short8*)arr;
    } else if (bid < 12288) {                // h cast
        long idx = (long)(bid - 4096) * 256 + tid;
        long b = idx >> 9; int hh = (int)(idx & 511);
        Agate[b * 768 + 256 + hh] = f2bf(h_prev[idx]);
    } else {                                 // z: 12288 rows x 512, 2 blocks/row
        int j = bid - 12288;
        int r = j >> 1, i = (j & 1) * 256 + tid;
        float v = z_prev[(long)r * 512 + i];
        zraw[(long)r * 512 + i] = f2bf(v);
        long ob = (long)r * 4608;
        Ze[ob + i] = f2bf(v / (1.f + __expf(-v)));
        short arr[8];
        spline8(v, arr);
        *(short8*)(Ze + ob + 512 + (long)i * 8) = *(const short8*)arr;
    }
}

// ---------------------------------------------------------------------------
// expand_pair: v = sum_s P[idx + s*sSplit] (fp32 split-K partials) ->
// silu+spline expansion (rows, inF*9); optional bf16 compact copy.
// 2 elems/thread, float2 loads. grid (inF/512, rows)
// ---------------------------------------------------------------------------
__global__ __launch_bounds__(256) void expand_pair(
    const float* __restrict__ P, long sSplit, int S, int inF,
    short* __restrict__ out, short* __restrict__ compact)
{
    int i = (blockIdx.x * 256 + threadIdx.x) * 2;
    int r = blockIdx.y;
    long idx = (long)r * inF + i;
    float2 v = *(const float2*)(P + idx);
    for (int s = 1; s < S; ++s) {
        float2 a = *(const float2*)(P + idx + (long)s * sSplit);
        v.x += a.x; v.y += a.y;
    }
    if (compact) { compact[idx] = f2bf(v.x); compact[idx + 1] = f2bf(v.y); }

    long ob = (long)r * inF * 9;
    out[ob + i]     = f2bf(v.x / (1.f + __expf(-v.x)));
    out[ob + i + 1] = f2bf(v.y / (1.f + __expf(-v.y)));

    short arr[8];
    spline8(v.x, arr);
    *(short8*)(out + ob + inF + (long)i * 8) = *(const short8*)arr;
    spline8(v.y, arr);
    *(short8*)(out + ob + inF + (long)(i + 1) * 8) = *(const short8*)arr;
}

// LayerNorm rows of 512 from fp32 split partials: out = LN(sum P + hh_b)*g + b
__global__ __launch_bounds__(256) void ln_pair(const float* __restrict__ P,
                                               long sSplit, int S,
                                               const float* __restrict__ hh_b,
                                               const float* __restrict__ ln_g,
                                               const float* __restrict__ ln_b,
                                               float* __restrict__ out)
{
    int row = blockIdx.x;
    int l = row >> 12;
    int t = threadIdx.x;
    long base = (long)row * 512;
    float v0 = hh_b[l * 512 + t];
    float v1 = hh_b[l * 512 + t + 256];
    for (int s = 0; s < S; ++s) {
        v0 += P[base + t + (long)s * sSplit];
        v1 += P[base + t + 256 + (long)s * sSplit];
    }
    float sm = v0 + v1, sq = v0 * v0 + v1 * v1;
#pragma unroll
    for (int off = 32; off; off >>= 1) {
        sm += __shfl_down(sm, off);
        sq += __shfl_down(sq, off);
    }
    __shared__ float ls[4], lq[4];
    int w = t >> 6, lane = t & 63;
    if (lane == 0) { ls[w] = sm; lq[w] = sq; }
    __syncthreads();
    float Sm = ls[0] + ls[1] + ls[2] + ls[3];
    float Q = lq[0] + lq[1] + lq[2] + lq[3];
    float mu = Sm * (1.f / 512.f);
    float var = Q * (1.f / 512.f) - mu * mu;
    float rstd = rsqrtf(var + 1e-5f);
    float* o = out + (long)row * 512;
    o[t]       = (v0 - mu) * rstd * ln_g[l * 512 + t]       + ln_b[l * 512 + t];
    o[t + 256] = (v1 - mu) * rstd * ln_g[l * 512 + t + 256] + ln_b[l * 512 + t + 256];
}

// final LSTM-style cell epilogue -> h_t, c_t
__global__ __launch_bounds__(256) void cell_epilogue(const short* __restrict__ gates,
                                                     const short* __restrict__ opre,
                                                     const float* __restrict__ c_prev,
                                                     const float* __restrict__ f_b,
                                                     const float* __restrict__ i_b,
                                                     const float* __restrict__ g_b,
                                                     const float* __restrict__ o_b,
                                                     float* __restrict__ out)
{
    long idx = blockIdx.x * 256L + threadIdx.x;
    long b = idx >> 9; int h = (int)(idx & 511);
    const short* g = gates + b * 1536;
    float fp = bf2f(g[h]) + f_b[h];
    float ip = bf2f(g[512 + h]) + i_b[h];
    float gp = bf2f(g[1024 + h]) + g_b[h];
    float op = bf2f(opre[idx]) + o_b[h];
    float ft = 1.f / (1.f + __expf(-fp));
    float it = 1.f / (1.f + __expf(-ip));
    float gt = tanhf(gp);
    float ot = 1.f / (1.f + __expf(-op));
    float c = ft * c_prev[idx] + it * gt;
    out[idx] = ot * tanhf(c);
    out[idx + 2097152] = c;
}

// ---------------------------------------------------------------------------
extern "C" void kernel_launch(void* const* d_in, const int* in_sizes, int n_in,
                              void* d_out, int out_size, void* d_ws, size_t ws_size,
                              hipStream_t stream)
{
    const float* x_t       = (const float*)d_in[0];
    const float* h_prev    = (const float*)d_in[1];
    const float* c_prev    = (const float*)d_in[2];
    const float* z_prev    = (const float*)d_in[3];
    const float* wx_base   = (const float*)d_in[4];
    const float* wx_spline = (const float*)d_in[5];
    const float* wh_base   = (const float*)d_in[6];
    const float* wh_spline = (const float*)d_in[7];
    const float* hz_base   = (const float*)d_in[8];
    const float* hz_spline = (const float*)d_in[9];
    const float* phi_base  = (const float*)d_in[10];
    const float* phi_spline= (const float*)d_in[11];
    const float* hh_w      = (const float*)d_in[12];
    const float* hh_b      = (const float*)d_in[13];
    const float* ln_g      = (const float*)d_in[14];
    const float* ln_b      = (const float*)d_in[15];
    const float* f_w       = (const float*)d_in[16];
    const float* f_b       = (const float*)d_in[17];
    const float* i_w       = (const float*)d_in[18];
    const float* i_b       = (const float*)d_in[19];
    const float* g_w       = (const float*)d_in[20];
    const float* g_b       = (const float*)d_in[21];
    const float* o_w       = (const float*)d_in[22];
    const float* o_b       = (const float*)d_in[23];
    float* out = (float*)d_out;
    const long BH = 4096L * 512;

    char* p = (char*)d_ws;
    auto alloc = [&](size_t bytes) {
        char* q = p;
        p += (bytes + 255) & ~(size_t)255;
        return q;
    };

    short* Wx   = (short*)alloc(3L * 512 * 2304 * 2);
    short* Wh   = (short*)alloc(3L * 512 * 4608 * 2);
    short* Whz  = (short*)alloc(3L * 512 * 4608 * 2);
    short* Wphi = (short*)alloc(3L * 512 * 4608 * 2);
    short* HHb  = (short*)alloc(3L * 512 * 512 * 2);
    short* OWb  = (short*)alloc(512L * 1536 * 2);
    short* Wg   = (short*)alloc(1536L * 768 * 2);
    short* Agate= (short*)alloc(4096L * 768 * 2);
    short* zraw = (short*)alloc(3L * 4096 * 512 * 2);
    short* XR   = (short*)alloc(4096L * 2304 * 2);      // Xe, later Rbuf
    short* Ebuf = (short*)alloc(3L * 4096 * 4608 * 2);  // Ze -> Se -> Oe -> gbuf/opre

    // split-K factor chosen from remaining workspace (4 if it fits, else 2)
    const long PS = 3L * 4096 * 512;                    // elems per split
    size_t used = (size_t)(p - (char*)d_ws);
    size_t splitB = (size_t)PS * 4;
    int S = (ws_size >= used + 4 * splitB + 4096) ? 4 : 2;
    float* Pbuf = (float*)alloc((size_t)S * splitB);

    short* Xe = XR;
    short* Rbuf = XR;
    short* gbuf = Ebuf;
    short* opre = Ebuf + 4096L * 1536;

    // ---- all weight packing in one launch ----
    megapack4<<<26880, 256, 0, stream>>>(
        wx_base, wx_spline, wh_base, wh_spline, hz_base, hz_spline,
        phi_base, phi_spline, hh_w, o_w, f_w, i_w, g_w,
        Wx, Wh, Whz, Wphi, HHb, OWb, Wg);

    // ---- all activation prep in one launch ----
    prep_acts<<<36864, 256, 0, stream>>>(x_t, h_prev, z_prev, Xe, Agate, Ebuf, zraw);

    // ---- s = Xe @ Wx^T + Ze @ Wh^T  (Ktot=6912) ----
    gemm256<<<dim3(16, 4, 3 * S), 512, 0, stream>>>(S, 6912 / S,
        Xe, 2304, 0, 2304,                 Wx, 2304, 512L * 2304,
        Ebuf, 4608, 4096L * 4608, 4608,    Wh, 4608, 512L * 4608,
        Pbuf, 512, 4096L * 512, PS);

    // ---- Se = expand(sum P), rows = z*4096+b ----
    expand_pair<<<dim3(1, 12288), 256, 0, stream>>>(Pbuf, PS, S, 512, Ebuf, (short*)0);

    // ---- o = Se @ Wphi^T (Ktot=4608) -> (B, L*512) fp32 partials ----
    gemm256<<<dim3(16, 4, 3 * S), 512, 0, stream>>>(S, 4608 / S,
        Ebuf, 4608, 4096L * 4608, 4608,    Wphi, 4608, 512L * 4608,
        zraw, 0, 0, 0,                     Wphi, 0, 0,
        Pbuf, 1536, 512, PS);

    // ---- Oe = expand(sum P) (rows = b*3+l); compact bf16 -> Rbuf ----
    expand_pair<<<dim3(1, 12288), 256, 0, stream>>>(Pbuf, PS, S, 512, Ebuf, Rbuf);

    // ---- zpre = Oe @ Whz^T + zraw @ hh_w^T (Ktot=5120) ----
    gemm256<<<dim3(16, 4, 3 * S), 512, 0, stream>>>(S, 5120 / S,
        Ebuf, 13824, 4608, 4608,           Whz, 4608, 512L * 4608,
        zraw, 512, 4096L * 512, 512,       HHb, 512, 512L * 512,
        Pbuf, 512, 4096L * 512, PS);

    // ---- z_all = LN(sum P + hh_b) ----
    ln_pair<<<12288, 256, 0, stream>>>(Pbuf, PS, S, hh_b, ln_g, ln_b, out + 2 * BH);

    // ---- gates (f,i,g) pre-activations (small GEMM: proven gemm64 path) ----
    gemm64<<<dim3(64, 12, 1), 256, 0, stream>>>(0,
        Agate, 768, 0, 768,  Wg, 768, 0,
        Agate, 768, 0, 0,    Wg, 768, 0,
        gbuf, 1536, 0);

    // ---- output gate pre-activation ----
    gemm64<<<dim3(64, 4, 1), 256, 0, stream>>>(0,
        Rbuf, 1536, 0, 1536, OWb, 1536, 0,
        Rbuf, 1536, 0, 0,    OWb, 1536, 0,
        opre, 512, 0);

    // ---- h_t, c_t ----
    cell_epilogue<<<8192, 256, 0, stream>>>(gbuf, opre, c_prev, f_b, i_b, g_b, o_b, out);
}

// Round 3
// 695.517 us; speedup vs baseline: 1.1074x; 1.1074x over previous
//
#include <hip/hip_runtime.h>

typedef __attribute__((ext_vector_type(8))) short short8;
typedef __attribute__((ext_vector_type(4))) float floatx4;

__device__ inline short f2bf(float v) {
    unsigned u = __builtin_bit_cast(unsigned, v);
    unsigned r = (u + 0x7fffu + ((u >> 16) & 1u)) >> 16;
    return (short)r;
}
__device__ inline float bf2f(short s) {
    unsigned u = ((unsigned)(unsigned short)s) << 16;
    return __builtin_bit_cast(float, u);
}

// spline weights for value v: 8 kept bases of the uniform cubic B-spline
__device__ inline void spline8(float v, short* arr) {
    float u = (v + 2.2f) * 2.5f;
    float fj = floorf(u);
    int jj = (int)fj;
    float t1 = u - fj;
    float ok = (jj >= 0 && jj <= 10) ? (1.f / 6.f) : 0.f;
    float t2 = t1 * t1, t3 = t2 * t1;
    float omt = 1.f - t1;
    short sw0 = f2bf(omt * omt * omt * ok);
    short sw1 = f2bf((3.f * t3 - 6.f * t2 + 4.f) * ok);
    short sw2 = f2bf((-3.f * t3 + 3.f * t2 + 3.f * t1 + 1.f) * ok);
    short sw3 = f2bf(t3 * ok);
#pragma unroll
    for (int s = 0; s < 8; ++s) {
        int rr = s - jj + 3;
        arr[s] = (rr == 0) ? sw0 : (rr == 1) ? sw1 : (rr == 2) ? sw2
                 : (rr == 3) ? sw3 : (short)0;
    }
}

// ---------------------------------------------------------------------------
// gemm128: 128x128 tile, BK=64, 4 waves (wave tile 64x64), proven 2-barrier
// global_load_lds schedule. BK=64 halves barrier/vmcnt-drain count vs BK=32.
// LDS XOR-swizzle (rule #21 both-sides): global source chunk pre-swizzled
// cg=((c^(c>>3))&7)*8 with LINEAR LDS dest; ds_read applies the same
// involution (chunk ^ (row&7)) -> wave's 64x16B read spreads over all 32
// banks at the structural floor. Split-K over concatenated 2-segment K;
// fp32 partials at C + s*sSplit. Grid (32,4,3*S); XCD remap: each XCD owns
// 4 M-slabs x 4 N per (z,s), N fastest so the A-slab stays in its L2.
// 3 blocks/CU (32KB LDS x3 = 96KB <= 160KB), grid 768 = 3/CU exact.
// ---------------------------------------------------------------------------
__global__ __launch_bounds__(256, 3) void gemm128(
    int S, int Kh,
    const short* __restrict__ A0, int lda0, long sA0, int K0,
    const short* __restrict__ W0, int ldw0, long sW0,
    const short* __restrict__ A1, int lda1, long sA1, int K1,
    const short* __restrict__ W1, int ldw1, long sW1,
    float* __restrict__ C, int ldc, long sC, long sSplit)
{
    __shared__ short As[128 * 64];
    __shared__ short Ws[128 * 64];
    const int t = threadIdx.x;
    // XCD remap; grid must be (32,4,Z)
    int n = blockIdx.x + (blockIdx.y << 5) + (blockIdx.z << 7);
    int k8 = n & 7, j = n >> 3;
    int byi = j & 3;
    int t2 = j >> 2;
    int bxi = k8 * 4 + (t2 & 3);
    int bzi = t2 >> 2;
    const int z = bzi / S, s = bzi % S;
    const int bm = bxi * 128, bn = byi * 128;
    const int lane = t & 63, w = t >> 6;
    const int wm = (w >> 1) * 64, wn = (w & 1) * 64;
    const int lrow = lane & 15, quad = lane >> 4;

    floatx4 acc[4][4] = {};

    const int kbeg = s * Kh, kend = kbeg + Kh;

    const short* A = A0 + (long)z * sA0;
    const short* W = W0 + (long)z * sW0;
    int lda = lda0, ldw = ldw0;
    int kb = kbeg, ke = (kend < K0) ? kend : K0;   // seg0 window

    for (int seg = 0; seg < 2; ++seg) {
        for (int kv = kb; kv < ke; kv += 64) {
#pragma unroll
            for (int i = 0; i < 4; ++i) {          // A,W: 128 rows x 8 chunks
                int c = i * 256 + t;
                int row = c >> 3;
                int cg = ((c ^ row) & 7) * 8;      // pre-swizzled source chunk
                const short* gp = A + (long)(bm + row) * lda + kv + cg;
                __builtin_amdgcn_global_load_lds(
                    (const __attribute__((address_space(1))) void*)gp,
                    (__attribute__((address_space(3))) void*)(As + c * 8), 16, 0, 0);
                const short* gq = W + (long)(bn + row) * ldw + kv + cg;
                __builtin_amdgcn_global_load_lds(
                    (const __attribute__((address_space(1))) void*)gq,
                    (__attribute__((address_space(3))) void*)(Ws + c * 8), 16, 0, 0);
            }
            __syncthreads();
#pragma unroll
            for (int kk = 0; kk < 2; ++kk) {
                short8 af[4], bfr[4];
#pragma unroll
                for (int mi = 0; mi < 4; ++mi) {
                    int r = wm + mi * 16 + lrow;
                    af[mi] = *(const short8*)(As + r * 64 +
                                              (((kk * 4 + quad) ^ (r & 7)) * 8));
                }
#pragma unroll
                for (int ni = 0; ni < 4; ++ni) {
                    int r = wn + ni * 16 + lrow;
                    bfr[ni] = *(const short8*)(Ws + r * 64 +
                                               (((kk * 4 + quad) ^ (r & 7)) * 8));
                }
#pragma unroll
                for (int mi = 0; mi < 4; ++mi)
#pragma unroll
                    for (int ni = 0; ni < 4; ++ni)
                        acc[mi][ni] = __builtin_amdgcn_mfma_f32_16x16x32_bf16(
                            af[mi], bfr[ni], acc[mi][ni], 0, 0, 0);
            }
            __syncthreads();
        }
        // segment-1 window (empty loop if this split doesn't reach seg1)
        A = A1 + (long)z * sA1;
        W = W1 + (long)z * sW1;
        lda = lda1; ldw = ldw1;
        kb = ((kbeg > K0) ? kbeg : K0) - K0;
        ke = kend - K0;
    }

    float* Cz = C + (long)z * sC + (long)s * sSplit;
#pragma unroll
    for (int mi = 0; mi < 4; ++mi)
#pragma unroll
        for (int ni = 0; ni < 4; ++ni)
#pragma unroll
            for (int r = 0; r < 4; ++r) {
                int row = bm + wm + mi * 16 + quad * 4 + r;
                int col = bn + wn + ni * 16 + lrow;
                Cz[(long)row * ldc + col] = acc[mi][ni][r];
            }
}

// ---------------------------------------------------------------------------
// gemm64: retained (round-4-proven) for the two small GEMMs (gates, ogate).
// Tile 64x128, BK=32, 4 waves, bf16 out. Called with swz=0 only.
// ---------------------------------------------------------------------------
__global__ __launch_bounds__(256) void gemm64(
    int swz,
    const short* __restrict__ A0, int lda0, long sA0, int K0,
    const short* __restrict__ W0, int ldw0, long sW0,
    const short* __restrict__ A1, int lda1, long sA1, int K1,
    const short* __restrict__ W1, int ldw1, long sW1,
    short* __restrict__ C, int ldc, long sC)
{
    __shared__ short As[64 * 32];
    __shared__ short Ws[128 * 32];
    const int t = threadIdx.x;
    int bxi = blockIdx.x, byi = blockIdx.y, bzi = blockIdx.z;
    if (swz) {                       // grid must be (64,4,3)
        int n = bxi + (byi << 6) + (bzi << 8);
        int k = n & 7, j = n >> 3;
        byi = j & 3;
        bxi = k * 8 + ((j >> 2) & 7);
        bzi = j >> 5;
    }
    const int z = bzi;
    const int bm = bxi * 64;
    const int bn = byi * 128;
    const int lane = t & 63, w = t >> 6;
    const int wm = (w >> 1) * 32, wn = (w & 1) * 64;
    const int lrow = lane & 15, quad = lane >> 4;

    floatx4 acc[2][4] = {};

    const short* A = A0 + (long)z * sA0;
    const short* W = W0 + (long)z * sW0;
    int K = K0, lda = lda0, ldw = ldw0;

    for (int seg = 0; seg < 2; ++seg) {
        for (int k0 = 0; k0 < K; k0 += 32) {
            {   // A: 64x32 = 256 16B chunks, one per thread
                int row = t >> 2, cg = (t & 3) * 8;
                const short* gp = A + (long)(bm + row) * lda + k0 + cg;
                __builtin_amdgcn_global_load_lds(
                    (const __attribute__((address_space(1))) void*)gp,
                    (__attribute__((address_space(3))) void*)(As + t * 8), 16, 0, 0);
            }
#pragma unroll
            for (int j = 0; j < 2; ++j) {  // W: 128x32 = 512 chunks, two per thread
                int cj = j * 256 + t;
                int row = cj >> 2, cg = (cj & 3) * 8;
                const short* gq = W + (long)(bn + row) * ldw + k0 + cg;
                __builtin_amdgcn_global_load_lds(
                    (const __attribute__((address_space(1))) void*)gq,
                    (__attribute__((address_space(3))) void*)(Ws + cj * 8), 16, 0, 0);
            }
            __syncthreads();
            short8 af[2], bfr[4];
#pragma unroll
            for (int mi = 0; mi < 2; ++mi)
                af[mi] = *(const short8*)(As + (wm + mi * 16 + lrow) * 32 + quad * 8);
#pragma unroll
            for (int ni = 0; ni < 4; ++ni)
                bfr[ni] = *(const short8*)(Ws + (wn + ni * 16 + lrow) * 32 + quad * 8);
#pragma unroll
            for (int mi = 0; mi < 2; ++mi)
#pragma unroll
                for (int ni = 0; ni < 4; ++ni)
                    acc[mi][ni] = __builtin_amdgcn_mfma_f32_16x16x32_bf16(
                        af[mi], bfr[ni], acc[mi][ni], 0, 0, 0);
            __syncthreads();
        }
        A = A1 + (long)z * sA1; W = W1 + (long)z * sW1;
        K = K1; lda = lda1; ldw = ldw1;
    }

    short* Cz = C + (long)z * sC;
#pragma unroll
    for (int mi = 0; mi < 2; ++mi)
#pragma unroll
        for (int ni = 0; ni < 4; ++ni)
#pragma unroll
            for (int r = 0; r < 4; ++r) {
                int row = bm + wm + mi * 16 + quad * 4 + r;
                int col = bn + wn + ni * 16 + lrow;
                Cz[(long)row * ldc + col] = f2bf(acc[mi][ni][r]);
            }
}

// ---------------------------------------------------------------------------
// megapack4: all weight fp32->bf16 packs, float4 loads / short4 stores.
// 4 elems/thread. grid: 26880 blocks x 256
// ---------------------------------------------------------------------------
__global__ __launch_bounds__(256) void megapack4(
    const float* __restrict__ wx_b, const float* __restrict__ wx_s,
    const float* __restrict__ wh_b, const float* __restrict__ wh_s,
    const float* __restrict__ hz_b, const float* __restrict__ hz_s,
    const float* __restrict__ phi_b, const float* __restrict__ phi_s,
    const float* __restrict__ hh_w, const float* __restrict__ o_w,
    const float* __restrict__ f_w, const float* __restrict__ i_w,
    const float* __restrict__ g_w,
    short* __restrict__ Wx, short* __restrict__ Wh, short* __restrict__ Whz,
    short* __restrict__ Wphi, short* __restrict__ HHb, short* __restrict__ OWb,
    short* __restrict__ Wg)
{
    int bid = blockIdx.x, tid = threadIdx.x;
    float4 v;
    short* dst;
    long e;
    if (bid < 3456) {                        // Wx: (1536, 2304) kan-pack
        e = ((long)bid * 256 + tid) * 4;
        int r = (int)(e / 2304), c = (int)(e % 2304);
        v = (c < 256) ? *(const float4*)(wx_b + (long)r * 256 + c)
                      : *(const float4*)(wx_s + (long)r * 2048 + (c - 256));
        dst = Wx + e;
    } else if (bid < 24192) {                // Wh/Whz/Wphi: (1536, 4608) each
        int jb = bid - 3456;
        int job = jb / 6912, lb = jb % 6912;
        const float* bp = (job == 0) ? wh_b : (job == 1) ? hz_b : phi_b;
        const float* sp = (job == 0) ? wh_s : (job == 1) ? hz_s : phi_s;
        short* dp = (job == 0) ? Wh : (job == 1) ? Whz : Wphi;
        e = ((long)lb * 256 + tid) * 4;
        int r = (int)(e / 4608), c = (int)(e % 4608);
        v = (c < 512) ? *(const float4*)(bp + (long)r * 512 + c)
                      : *(const float4*)(sp + (long)r * 4096 + (c - 512));
        dst = dp + e;
    } else if (bid < 24960) {                // hh_w flat 786432
        e = ((long)(bid - 24192) * 256 + tid) * 4;
        v = *(const float4*)(hh_w + e);
        dst = HHb + e;
    } else if (bid < 25728) {                // o_w flat 786432
        e = ((long)(bid - 24960) * 256 + tid) * 4;
        v = *(const float4*)(o_w + e);
        dst = OWb + e;
    } else if (bid < 26112) {                // f_w flat 393216
        e = ((long)(bid - 25728) * 256 + tid) * 4;
        v = *(const float4*)(f_w + e);
        dst = Wg + e;
    } else if (bid < 26496) {                // i_w
        e = ((long)(bid - 26112) * 256 + tid) * 4;
        v = *(const float4*)(i_w + e);
        dst = Wg + 393216 + e;
    } else {                                 // g_w
        e = ((long)(bid - 26496) * 256 + tid) * 4;
        v = *(const float4*)(g_w + e);
        dst = Wg + 786432 + e;
    }
    dst[0] = f2bf(v.x); dst[1] = f2bf(v.y);
    dst[2] = f2bf(v.z); dst[3] = f2bf(v.w);
}

// ---------------------------------------------------------------------------
// prep_acts: x expand -> Xe + Agate[:,0:256]; h cast -> Agate[:,256:768];
// z expand -> Ze + zraw.  grid: 36864 blocks x 256
// ---------------------------------------------------------------------------
__global__ __launch_bounds__(256) void prep_acts(
    const float* __restrict__ x_t, const float* __restrict__ h_prev,
    const float* __restrict__ z_prev,
    short* __restrict__ Xe, short* __restrict__ Agate,
    short* __restrict__ Ze, short* __restrict__ zraw)
{
    int bid = blockIdx.x, tid = threadIdx.x;
    if (bid < 4096) {                        // x: row bid, col tid
        int r = bid, i = tid;
        float v = x_t[(long)r * 256 + i];
        Agate[(long)r * 768 + i] = f2bf(v);
        long ob = (long)r * 2304;
        Xe[ob + i] = f2bf(v / (1.f + __expf(-v)));
        short arr[8];
        spline8(v, arr);
        *(short8*)(Xe + ob + 256 + (long)i * 8) = *(const short8*)arr;
    } else if (bid < 12288) {                // h cast
        long idx = (long)(bid - 4096) * 256 + tid;
        long b = idx >> 9; int hh = (int)(idx & 511);
        Agate[b * 768 + 256 + hh] = f2bf(h_prev[idx]);
    } else {                                 // z: 12288 rows x 512, 2 blocks/row
        int j = bid - 12288;
        int r = j >> 1, i = (j & 1) * 256 + tid;
        float v = z_prev[(long)r * 512 + i];
        zraw[(long)r * 512 + i] = f2bf(v);
        long ob = (long)r * 4608;
        Ze[ob + i] = f2bf(v / (1.f + __expf(-v)));
        short arr[8];
        spline8(v, arr);
        *(short8*)(Ze + ob + 512 + (long)i * 8) = *(const short8*)arr;
    }
}

// ---------------------------------------------------------------------------
// expand_pair: v = sum_s P[idx + s*sSplit] (fp32 split-K partials) ->
// silu+spline expansion (rows, inF*9); optional bf16 compact copy.
// 2 elems/thread, float2 loads. grid (inF/512, rows)
// ---------------------------------------------------------------------------
__global__ __launch_bounds__(256) void expand_pair(
    const float* __restrict__ P, long sSplit, int S, int inF,
    short* __restrict__ out, short* __restrict__ compact)
{
    int i = (blockIdx.x * 256 + threadIdx.x) * 2;
    int r = blockIdx.y;
    long idx = (long)r * inF + i;
    float2 v = *(const float2*)(P + idx);
    for (int s = 1; s < S; ++s) {
        float2 a = *(const float2*)(P + idx + (long)s * sSplit);
        v.x += a.x; v.y += a.y;
    }
    if (compact) { compact[idx] = f2bf(v.x); compact[idx + 1] = f2bf(v.y); }

    long ob = (long)r * inF * 9;
    out[ob + i]     = f2bf(v.x / (1.f + __expf(-v.x)));
    out[ob + i + 1] = f2bf(v.y / (1.f + __expf(-v.y)));

    short arr[8];
    spline8(v.x, arr);
    *(short8*)(out + ob + inF + (long)i * 8) = *(const short8*)arr;
    spline8(v.y, arr);
    *(short8*)(out + ob + inF + (long)(i + 1) * 8) = *(const short8*)arr;
}

// ---------------------------------------------------------------------------
// ln_wave: LayerNorm rows of 512, ONE WAVE PER ROW (no __syncthreads).
// 8 elems/lane, float4 I/O, shuffle-reduce. grid: 3072 blocks x 256 (4 rows)
// ---------------------------------------------------------------------------
__global__ __launch_bounds__(256) void ln_wave(const float* __restrict__ P,
                                               long sSplit, int S,
                                               const float* __restrict__ hh_b,
                                               const float* __restrict__ ln_g,
                                               const float* __restrict__ ln_b,
                                               float* __restrict__ out)
{
    int wv = threadIdx.x >> 6, lane = threadIdx.x & 63;
    int row = blockIdx.x * 4 + wv;           // [0, 12288)
    int l = row >> 12;
    int col = lane * 8;
    long base = (long)row * 512 + col;
    float v[8];
#pragma unroll
    for (int e = 0; e < 8; ++e) v[e] = hh_b[l * 512 + col + e];
    for (int s = 0; s < S; ++s) {
        float4 a = *(const float4*)(P + base + (long)s * sSplit);
        float4 b = *(const float4*)(P + base + 4 + (long)s * sSplit);
        v[0] += a.x; v[1] += a.y; v[2] += a.z; v[3] += a.w;
        v[4] += b.x; v[5] += b.y; v[6] += b.z; v[7] += b.w;
    }
    float sm = 0.f, sq = 0.f;
#pragma unroll
    for (int e = 0; e < 8; ++e) { sm += v[e]; sq += v[e] * v[e]; }
#pragma unroll
    for (int off = 32; off; off >>= 1) {
        sm += __shfl_down(sm, off);
        sq += __shfl_down(sq, off);
    }
    sm = __shfl(sm, 0);
    sq = __shfl(sq, 0);
    float mu = sm * (1.f / 512.f);
    float var = sq * (1.f / 512.f) - mu * mu;
    float rstd = rsqrtf(var + 1e-5f);
    float o[8];
#pragma unroll
    for (int e = 0; e < 8; ++e)
        o[e] = (v[e] - mu) * rstd * ln_g[l * 512 + col + e] + ln_b[l * 512 + col + e];
    float* op = out + base;
    *(float4*)op = make_float4(o[0], o[1], o[2], o[3]);
    *(float4*)(op + 4) = make_float4(o[4], o[5], o[6], o[7]);
}

// final LSTM-style cell epilogue -> h_t, c_t
__global__ __launch_bounds__(256) void cell_epilogue(const short* __restrict__ gates,
                                                     const short* __restrict__ opre,
                                                     const float* __restrict__ c_prev,
                                                     const float* __restrict__ f_b,
                                                     const float* __restrict__ i_b,
                                                     const float* __restrict__ g_b,
                                                     const float* __restrict__ o_b,
                                                     float* __restrict__ out)
{
    long idx = blockIdx.x * 256L + threadIdx.x;
    long b = idx >> 9; int h = (int)(idx & 511);
    const short* g = gates + b * 1536;
    float fp = bf2f(g[h]) + f_b[h];
    float ip = bf2f(g[512 + h]) + i_b[h];
    float gp = bf2f(g[1024 + h]) + g_b[h];
    float op = bf2f(opre[idx]) + o_b[h];
    float ft = 1.f / (1.f + __expf(-fp));
    float it = 1.f / (1.f + __expf(-ip));
    float gt = tanhf(gp);
    float ot = 1.f / (1.f + __expf(-op));
    float c = ft * c_prev[idx] + it * gt;
    out[idx] = ot * tanhf(c);
    out[idx + 2097152] = c;
}

// ---------------------------------------------------------------------------
extern "C" void kernel_launch(void* const* d_in, const int* in_sizes, int n_in,
                              void* d_out, int out_size, void* d_ws, size_t ws_size,
                              hipStream_t stream)
{
    const float* x_t       = (const float*)d_in[0];
    const float* h_prev    = (const float*)d_in[1];
    const float* c_prev    = (const float*)d_in[2];
    const float* z_prev    = (const float*)d_in[3];
    const float* wx_base   = (const float*)d_in[4];
    const float* wx_spline = (const float*)d_in[5];
    const float* wh_base   = (const float*)d_in[6];
    const float* wh_spline = (const float*)d_in[7];
    const float* hz_base   = (const float*)d_in[8];
    const float* hz_spline = (const float*)d_in[9];
    const float* phi_base  = (const float*)d_in[10];
    const float* phi_spline= (const float*)d_in[11];
    const float* hh_w      = (const float*)d_in[12];
    const float* hh_b      = (const float*)d_in[13];
    const float* ln_g      = (const float*)d_in[14];
    const float* ln_b      = (const float*)d_in[15];
    const float* f_w       = (const float*)d_in[16];
    const float* f_b       = (const float*)d_in[17];
    const float* i_w       = (const float*)d_in[18];
    const float* i_b       = (const float*)d_in[19];
    const float* g_w       = (const float*)d_in[20];
    const float* g_b       = (const float*)d_in[21];
    const float* o_w       = (const float*)d_in[22];
    const float* o_b       = (const float*)d_in[23];
    float* out = (float*)d_out;
    const long BH = 4096L * 512;

    char* p = (char*)d_ws;
    auto alloc = [&](size_t bytes) {
        char* q = p;
        p += (bytes + 255) & ~(size_t)255;
        return q;
    };

    short* Wx   = (short*)alloc(3L * 512 * 2304 * 2);
    short* Wh   = (short*)alloc(3L * 512 * 4608 * 2);
    short* Whz  = (short*)alloc(3L * 512 * 4608 * 2);
    short* Wphi = (short*)alloc(3L * 512 * 4608 * 2);
    short* HHb  = (short*)alloc(3L * 512 * 512 * 2);
    short* OWb  = (short*)alloc(512L * 1536 * 2);
    short* Wg   = (short*)alloc(1536L * 768 * 2);
    short* Agate= (short*)alloc(4096L * 768 * 2);
    short* zraw = (short*)alloc(3L * 4096 * 512 * 2);
    short* XR   = (short*)alloc(4096L * 2304 * 2);      // Xe, later Rbuf
    short* Ebuf = (short*)alloc(3L * 4096 * 4608 * 2);  // Ze -> Se -> Oe -> gbuf/opre

    const int S = 2;                                    // split-K factor
    const long PS = 3L * 4096 * 512;                    // elems per split
    float* Pbuf = (float*)alloc((size_t)S * PS * 4);    // fp32 partials

    short* Xe = XR;
    short* Rbuf = XR;
    short* gbuf = Ebuf;
    short* opre = Ebuf + 4096L * 1536;

    // ---- all weight packing in one launch ----
    megapack4<<<26880, 256, 0, stream>>>(
        wx_base, wx_spline, wh_base, wh_spline, hz_base, hz_spline,
        phi_base, phi_spline, hh_w, o_w, f_w, i_w, g_w,
        Wx, Wh, Whz, Wphi, HHb, OWb, Wg);

    // ---- all activation prep in one launch ----
    prep_acts<<<36864, 256, 0, stream>>>(x_t, h_prev, z_prev, Xe, Agate, Ebuf, zraw);

    // ---- s = Xe @ Wx^T + Ze @ Wh^T  (Ktot=6912, split 3456/3456) ----
    gemm128<<<dim3(32, 4, 3 * S), 256, 0, stream>>>(S, 3456,
        Xe, 2304, 0, 2304,                 Wx, 2304, 512L * 2304,
        Ebuf, 4608, 4096L * 4608, 4608,    Wh, 4608, 512L * 4608,
        Pbuf, 512, 4096L * 512, PS);

    // ---- Se = expand(sum P), rows = z*4096+b ----
    expand_pair<<<dim3(1, 12288), 256, 0, stream>>>(Pbuf, PS, S, 512, Ebuf, (short*)0);

    // ---- o = Se @ Wphi^T (Ktot=4608, split 2304/2304) -> (B, L*512) fp32 ----
    gemm128<<<dim3(32, 4, 3 * S), 256, 0, stream>>>(S, 2304,
        Ebuf, 4608, 4096L * 4608, 4608,    Wphi, 4608, 512L * 4608,
        zraw, 0, 0, 0,                     Wphi, 0, 0,
        Pbuf, 1536, 512, PS);

    // ---- Oe = expand(sum P) (rows = b*3+l); compact bf16 -> Rbuf ----
    expand_pair<<<dim3(1, 12288), 256, 0, stream>>>(Pbuf, PS, S, 512, Ebuf, Rbuf);

    // ---- zpre = Oe @ Whz^T + zraw @ hh_w^T (Ktot=5120, split 2560/2560) ----
    gemm128<<<dim3(32, 4, 3 * S), 256, 0, stream>>>(S, 2560,
        Ebuf, 13824, 4608, 4608,           Whz, 4608, 512L * 4608,
        zraw, 512, 4096L * 512, 512,       HHb, 512, 512L * 512,
        Pbuf, 512, 4096L * 512, PS);

    // ---- z_all = LN(sum P + hh_b) ----
    ln_wave<<<3072, 256, 0, stream>>>(Pbuf, PS, S, hh_b, ln_g, ln_b, out + 2 * BH);

    // ---- gates (f,i,g) pre-activations (small GEMM: proven gemm64 path) ----
    gemm64<<<dim3(64, 12, 1), 256, 0, stream>>>(0,
        Agate, 768, 0, 768,  Wg, 768, 0,
        Agate, 768, 0, 0,    Wg, 768, 0,
        gbuf, 1536, 0);

    // ---- output gate pre-activation ----
    gemm64<<<dim3(64, 4, 1), 256, 0, stream>>>(0,
        Rbuf, 1536, 0, 1536, OWb, 1536, 0,
        Rbuf, 1536, 0, 0,    OWb, 1536, 0,
        opre, 512, 0);

    // ---- h_t, c_t ----
    cell_epilogue<<<8192, 256, 0, stream>>>(gbuf, opre, c_prev, f_b, i_b, g_b, o_b, out);
}